// Round 20
// baseline (34.333 us; speedup 1.0000x reference)
//
#include <hip/hip_runtime.h>

// SphericalVectorPool on MI355X — k-split for VGPR residency.
// Theory: R18's ~130 VGPR sat just above the 128 tier boundary -> 2 waves/SIMD
// -> 75% issue bubbles. Split: 1 wave = (anchor, half of the 16 k-values).
// 8192 waves, acc v[32], ~85 VGPR, __launch_bounds__(64,4) -> 4 waves/SIMD.
// k-halves are sqrt-chain families (mu_j = 4/j => E_{j/2}=E_j^2):
//   kh0: j in {16,12, 8,6,4,3,2,1}  = heads E16,E12 + 6 squarings
//   kh1: j in {14,10, 7,5, 9,11,13,15} = heads E14,E10 + 2 sq + 4 direct exps
// f16 dot2 accumulation; 5-stage transpose-reduce + shfl_xor(32); 32-lane store.

constexpr int NR    = 16;
constexpr int BATCH = 2;
constexpr int NSRC  = 2048;
constexpr int MOUT  = 2048;

typedef __fp16 h2 __attribute__((ext_vector_type(2)));

#define STAGE(P, CNT)                                                     \
    {                                                                     \
        const bool mybit = (lane >> (P)) & 1;                             \
        _Pragma("unroll")                                                 \
        for (int t = 0; t < ((CNT) / 2); ++t) {                           \
            const float lo = v[2 * t], hi = v[2 * t + 1];                 \
            const float send = mybit ? lo : hi;                           \
            const float keep = mybit ? hi : lo;                           \
            v[t] = keep + __shfl_xor(send, 1 << (P), 64);                 \
        }                                                                 \
    }

__global__ __launch_bounds__(64, 4) void svp_kernel(
    const float* __restrict__ f,       // [B,N]
    const float* __restrict__ coords,  // [B,N,3]
    const float* __restrict__ outc,    // [B,M,3]
    const float* __restrict__ mu,      // [16]
    const float* __restrict__ rn,      // [16]
    const float* __restrict__ an0,     // [1]
    const float* __restrict__ an1,     // [1]
    float* __restrict__ out)           // [B,M,64]
{
    const int lane = threadIdx.x;             // 0..63, one wave per block
    const int wid  = blockIdx.x;              // 0..8191
    const int anchor = wid >> 1;              // 0..4095
    const int kh = wid & 1;                   // k-half
    const int b = anchor >> 11;

    const float NL2E = -1.44269504088896340736f;

    const float Rx = outc[(size_t)anchor * 3 + 0];
    const float Ry = outc[(size_t)anchor * 3 + 1];
    const float Rz = outc[(size_t)anchor * 3 + 2];

    // slot -> mu-index (j-1) map per half (compile-time)
    // kh0 slots: {16,12,8,6,4,3,2,1} ; kh1 slots: {14,10,7,5,9,11,13,15}
    const int km0[8] = {15, 11, 7, 5, 3, 2, 1, 0};
    const int km1[8] = {13,  9, 6, 4, 8, 10, 12, 14};

    float v[32];
#pragma unroll
    for (int j = 0; j < 32; ++j) v[j] = 0.f;

    const float* cb = coords + (size_t)b * NSRC * 3;
    const float* fb = f + (size_t)b * NSRC;

    for (int i = 0; i < NSRC / 128; ++i) {    // 16 iterations, 2 src/lane
        const int sA = i * 128 + lane;
        const int sB = sA + 64;
        const float cxA = cb[sA * 3 + 0], cyA = cb[sA * 3 + 1], czA = cb[sA * 3 + 2];
        const float cxB = cb[sB * 3 + 0], cyB = cb[sB * 3 + 1], czB = cb[sB * 3 + 2];
        const float fvA = fb[sA], fvB = fb[sB];

        const float dxA = cxA - Rx, dyA = cyA - Ry, dzA = czA - Rz;
        const float dxB = cxB - Rx, dyB = cyB - Ry, dzB = czB - Rz;
        const float sqA = dxA * dxA + dyA * dyA + dzA * dzA;
        const float sqB = dxB * dxB + dyB * dyB + dzB * dzB;
        const float riA = __builtin_amdgcn_rsqf(sqA);
        const float riB = __builtin_amdgcn_rsqf(sqB);
        const float ddA = (sqA * riA) * NL2E;   // -log2e * |r-R|
        const float ddB = (sqB * riB) * NL2E;
        const float tA  = fvA * riA, tB = fvB * riB;
        const float fxA = tA * dxA, fyA = tA * dyA, fzA = tA * dzA;
        const float fxB = tB * dxB, fyB = tB * dyB, fzB = tB * dzB;

        float eA[8], eB[8];
        if (kh == 0) {
            // heads E16, E12; squarings for 8,6,4,3,2,1
            eA[0] = __builtin_amdgcn_exp2f(ddA * mu[15]);   // E16
            eA[1] = __builtin_amdgcn_exp2f(ddA * mu[11]);   // E12
            eA[2] = eA[0] * eA[0];   // E8
            eA[3] = eA[1] * eA[1];   // E6
            eA[4] = eA[2] * eA[2];   // E4
            eA[5] = eA[3] * eA[3];   // E3
            eA[6] = eA[4] * eA[4];   // E2
            eA[7] = eA[6] * eA[6];   // E1
            eB[0] = __builtin_amdgcn_exp2f(ddB * mu[15]);
            eB[1] = __builtin_amdgcn_exp2f(ddB * mu[11]);
            eB[2] = eB[0] * eB[0];
            eB[3] = eB[1] * eB[1];
            eB[4] = eB[2] * eB[2];
            eB[5] = eB[3] * eB[3];
            eB[6] = eB[4] * eB[4];
            eB[7] = eB[6] * eB[6];
        } else {
            // heads E14, E10 (-> E7, E5); direct E9, E11, E13, E15
            eA[0] = __builtin_amdgcn_exp2f(ddA * mu[13]);   // E14
            eA[1] = __builtin_amdgcn_exp2f(ddA * mu[9]);    // E10
            eA[2] = eA[0] * eA[0];   // E7
            eA[3] = eA[1] * eA[1];   // E5
            eA[4] = __builtin_amdgcn_exp2f(ddA * mu[8]);    // E9
            eA[5] = __builtin_amdgcn_exp2f(ddA * mu[10]);   // E11
            eA[6] = __builtin_amdgcn_exp2f(ddA * mu[12]);   // E13
            eA[7] = __builtin_amdgcn_exp2f(ddA * mu[14]);   // E15
            eB[0] = __builtin_amdgcn_exp2f(ddB * mu[13]);
            eB[1] = __builtin_amdgcn_exp2f(ddB * mu[9]);
            eB[2] = eB[0] * eB[0];
            eB[3] = eB[1] * eB[1];
            eB[4] = __builtin_amdgcn_exp2f(ddB * mu[8]);
            eB[5] = __builtin_amdgcn_exp2f(ddB * mu[10]);
            eB[6] = __builtin_amdgcn_exp2f(ddB * mu[12]);
            eB[7] = __builtin_amdgcn_exp2f(ddB * mu[14]);
        }

        const h2 wv = __builtin_amdgcn_cvt_pkrtz(fvA, fvB);
        const h2 wx = __builtin_amdgcn_cvt_pkrtz(fxA, fxB);
        const h2 wy = __builtin_amdgcn_cvt_pkrtz(fyA, fyB);
        const h2 wz = __builtin_amdgcn_cvt_pkrtz(fzA, fzB);

#pragma unroll
        for (int s = 0; s < 8; ++s) {
            const h2 ek = __builtin_amdgcn_cvt_pkrtz(eA[s], eB[s]);
            v[s]      = __builtin_amdgcn_fdot2(ek, wv, v[s],      false);
            v[8 + s]  = __builtin_amdgcn_fdot2(ek, wx, v[8 + s],  false);
            v[16 + s] = __builtin_amdgcn_fdot2(ek, wy, v[16 + s], false);
            v[24 + s] = __builtin_amdgcn_fdot2(ek, wz, v[24 + s], false);
        }
    }

    // 5-stage transpose-reduce over 32 accs, then fold the two lane-halves.
    STAGE(0, 32) STAGE(1, 16) STAGE(2, 8) STAGE(3, 4) STAGE(4, 2)
    float r = v[0];
    r += __shfl_xor(r, 32, 64);
    // lane l (0..63): r = total for acc index (l & 31); acc = c*8 + s.

    if (lane < 32) {
        const int c = lane >> 3;              // component 0..3
        const int s = lane & 7;               // slot 0..7
        const int km = (kh == 0) ? km0[s] : km1[s];
        const float sc = rn[km] * (c == 0 ? an0[0] : an1[0]);
        out[(size_t)anchor * 64 + c * 16 + km] = r * sc;
    }
}

extern "C" void kernel_launch(void* const* d_in, const int* in_sizes, int n_in,
                              void* d_out, int out_size, void* d_ws, size_t ws_size,
                              hipStream_t stream) {
    const float* f      = (const float*)d_in[0];
    const float* coords = (const float*)d_in[1];
    const float* outc   = (const float*)d_in[2];
    const float* mu     = (const float*)d_in[3];
    const float* rn     = (const float*)d_in[4];
    const float* an0    = (const float*)d_in[5];
    const float* an1    = (const float*)d_in[6];
    float* out = (float*)d_out;

    const int nwaves = BATCH * MOUT * 2;           // 8192 waves, 1 per block
    svp_kernel<<<nwaves, 64, 0, stream>>>(f, coords, outc, mu, rn, an0, an1, out);
}

// Round 21
// 28.196 us; speedup vs baseline: 1.2177x; 1.2177x over previous
//
#include <hip/hip_runtime.h>

// SphericalVectorPool on MI355X — packed-f16 sqrt-chain (derived E in h2).
// Model from R1-R20: wall ∝ total wave-instructions (~7 cyc/instr effective);
// only count reductions ever moved the needle. R18 budget 148/pair; this
// round halves the derived-E path: cvt the 8 exp HEADS to packed (A,B) f16
// (8 cvt), then derive the 8 squares in packed f16 via v_pk_mul_f16 (8
// instrs, already in dot2 operand layout) — replaces 16 f32 muls + 16 cvt.
// E1..E8 cascade error <=1.5e-2 rel, negligible absolutely (E small at
// typical d). 1 wave = 1 anchor, fused loads, f16 dot2 accumulate,
// bit-compaction transpose-reduce, 256B store.

constexpr int NR    = 16;
constexpr int BATCH = 2;
constexpr int NSRC  = 2048;
constexpr int MOUT  = 2048;

typedef __fp16 h2 __attribute__((ext_vector_type(2)));

#define STAGE(P, CNT)                                                     \
    {                                                                     \
        const bool mybit = (lane >> (P)) & 1;                             \
        _Pragma("unroll")                                                 \
        for (int t = 0; t < ((CNT) / 2); ++t) {                           \
            const float lo = v[2 * t], hi = v[2 * t + 1];                 \
            const float send = mybit ? lo : hi;                           \
            const float keep = mybit ? hi : lo;                           \
            v[t] = keep + __shfl_xor(send, 1 << (P), 64);                 \
        }                                                                 \
    }

__global__ __launch_bounds__(64, 1) void svp_kernel(
    const float* __restrict__ f,       // [B,N]
    const float* __restrict__ coords,  // [B,N,3]
    const float* __restrict__ outc,    // [B,M,3]
    const float* __restrict__ mu,      // [16]
    const float* __restrict__ rn,      // [16]
    const float* __restrict__ an0,     // [1]
    const float* __restrict__ an1,     // [1]
    float* __restrict__ out)           // [B,M,64]
{
    const int lane = threadIdx.x;             // 0..63, one wave per block
    const int anchor = blockIdx.x;            // 0..4095
    const int b = anchor >> 11;

    const float NL2E = -1.44269504088896340736f;

    const float Rx = outc[(size_t)anchor * 3 + 0];
    const float Ry = outc[(size_t)anchor * 3 + 1];
    const float Rz = outc[(size_t)anchor * 3 + 2];

    float v[64];
#pragma unroll
    for (int j = 0; j < 64; ++j) v[j] = 0.f;

    const float* cb = coords + (size_t)b * NSRC * 3;
    const float* fb = f + (size_t)b * NSRC;

    for (int i = 0; i < NSRC / 128; ++i) {    // 16 iterations, 2 src/lane
        const int sA = i * 128 + lane;
        const int sB = sA + 64;
        const float cxA = cb[sA * 3 + 0], cyA = cb[sA * 3 + 1], czA = cb[sA * 3 + 2];
        const float cxB = cb[sB * 3 + 0], cyB = cb[sB * 3 + 1], czB = cb[sB * 3 + 2];
        const float fvA = fb[sA], fvB = fb[sB];

        const float dxA = cxA - Rx, dyA = cyA - Ry, dzA = czA - Rz;
        const float dxB = cxB - Rx, dyB = cyB - Ry, dzB = czB - Rz;
        const float sqA = dxA * dxA + dyA * dyA + dzA * dzA;
        const float sqB = dxB * dxB + dyB * dyB + dzB * dzB;
        const float riA = __builtin_amdgcn_rsqf(sqA);
        const float riB = __builtin_amdgcn_rsqf(sqB);
        const float ddA = (sqA * riA) * NL2E;   // -log2e * |r-R|
        const float ddB = (sqB * riB) * NL2E;
        const float tA  = fvA * riA, tB = fvB * riB;
        const float fxA = tA * dxA, fyA = tA * dyA, fzA = tA * dzA;
        const float fxB = tB * dxB, fyB = tB * dyB, fzB = tB * dzB;

        // 8 exp heads per source (j = 16..9), packed to (A,B) f16 pairs.
        // ep[s] = packed E_{16-s}; derived squares in packed f16:
        //   E8=E16^2, E7=E14^2, E6=E12^2, E5=E10^2,
        //   E4=E8^2,  E3=E6^2,  E2=E4^2,  E1=E2^2
        h2 ep[16];   // index: 0..7 heads j=16..9 ; 8..15 derived j=8..1
#pragma unroll
        for (int s = 0; s < 8; ++s) {
            const float m_k = mu[15 - s];       // j = 16-s
            ep[s] = __builtin_amdgcn_cvt_pkrtz(
                __builtin_amdgcn_exp2f(ddA * m_k),
                __builtin_amdgcn_exp2f(ddB * m_k));
        }
        ep[8]  = ep[0] * ep[0];    // E8  = E16^2  (v_pk_mul_f16)
        ep[9]  = ep[2] * ep[2];    // E7  = E14^2
        ep[10] = ep[4] * ep[4];    // E6  = E12^2
        ep[11] = ep[6] * ep[6];    // E5  = E10^2
        ep[12] = ep[8] * ep[8];    // E4  = E8^2
        ep[13] = ep[10] * ep[10];  // E3  = E6^2
        ep[14] = ep[12] * ep[12];  // E2  = E4^2
        ep[15] = ep[14] * ep[14];  // E1  = E2^2

        const h2 wv = __builtin_amdgcn_cvt_pkrtz(fvA, fvB);
        const h2 wx = __builtin_amdgcn_cvt_pkrtz(fxA, fxB);
        const h2 wy = __builtin_amdgcn_cvt_pkrtz(fyA, fyB);
        const h2 wz = __builtin_amdgcn_cvt_pkrtz(fzA, fzB);

        // slot s holds E_j with j = 16-s (s<8) or j = 8-(s-8) (s>=8):
        // k-index (j-1): s<8 -> 15-s ; s>=8 -> 15-s+8... compute map:
#pragma unroll
        for (int s = 0; s < 16; ++s) {
            const int k = (s < 8) ? (15 - s) : (15 - s);  // j-1 = 15-s for heads
            // heads: j=16-s -> k=15-s ✓ ; derived: j=8-(s-8)=16-s -> k=15-s ✓
            v[k]      = __builtin_amdgcn_fdot2(ep[s], wv, v[k],      false);
            v[16 + k] = __builtin_amdgcn_fdot2(ep[s], wx, v[16 + k], false);
            v[32 + k] = __builtin_amdgcn_fdot2(ep[s], wy, v[32 + k], false);
            v[48 + k] = __builtin_amdgcn_fdot2(ep[s], wz, v[48 + k], false);
        }
    }

    STAGE(0, 64) STAGE(1, 32) STAGE(2, 16) STAGE(3, 8) STAGE(4, 4) STAGE(5, 2)
    // lane j now holds output j summed over all 64 lanes (= all 2048 sources)

    const float s = rn[lane & (NR - 1)] * (lane < NR ? an0[0] : an1[0]);
    out[(size_t)anchor * 64 + lane] = v[0] * s;
}

extern "C" void kernel_launch(void* const* d_in, const int* in_sizes, int n_in,
                              void* d_out, int out_size, void* d_ws, size_t ws_size,
                              hipStream_t stream) {
    const float* f      = (const float*)d_in[0];
    const float* coords = (const float*)d_in[1];
    const float* outc   = (const float*)d_in[2];
    const float* mu     = (const float*)d_in[3];
    const float* rn     = (const float*)d_in[4];
    const float* an0    = (const float*)d_in[5];
    const float* an1    = (const float*)d_in[6];
    float* out = (float*)d_out;

    const int anchors = BATCH * MOUT;              // 4096 waves, 1 per block
    svp_kernel<<<anchors, 64, 0, stream>>>(f, coords, outc, mu, rn, an0, an1, out);
}

// Round 22
// 25.509 us; speedup vs baseline: 1.3459x; 1.1053x over previous
//
#include <hip/hip_runtime.h>

// SphericalVectorPool on MI355X — MFMA contraction (v_mfma_f32_16x16x32_f16).
// Per anchor: D[16 k][4 comp] = sum_src E[k][src] * w[src][comp] — exactly one
// MFMA per 32-source chunk, accumulating f32. E generated in lane=source
// layout with the mu_j=4/j sqrt-chain (8 exp + 8 pk_mul per 2 sources, max
// eval density), then transposed to fragment layout via LDS:
//   eT[k][src] f16 (stride 136 = 4-way-max bank pattern). Lane s handles
//   sources (2s,2s+1) so each h2 is src-contiguous -> 1 ds_write_b32/row.
//   A-frag(lane l, e) = E[row=l&15][K=4*(l>>4)+e | 16+...] = 2 ds_read_b64.
//   B-frag = w_comp[same K] from wT[comp][src] (cols>=4 duplicate col&3).
// K-permutation is contraction-invariant (same map on A and B), so only the
// M/N roles carry layout risk; D-map is m89-verified (col=lane&15,
// row=4*(lane>>4)+reg). Epilogue: D scales -> direct dwordx4 store (no
// shuffle reduce at all). VALU/iter ~80 vs ~140; MACs move to MFMA pipe.

constexpr int NR    = 16;
constexpr int BATCH = 2;
constexpr int NSRC  = 2048;
constexpr int MOUT  = 2048;

typedef __fp16 h2 __attribute__((ext_vector_type(2)));
typedef _Float16 f16x8 __attribute__((ext_vector_type(8)));
typedef float f32x4 __attribute__((ext_vector_type(4)));

__global__ __launch_bounds__(64, 1) void svp_kernel(
    const float* __restrict__ f,       // [B,N]
    const float* __restrict__ coords,  // [B,N,3]
    const float* __restrict__ outc,    // [B,M,3]
    const float* __restrict__ mu,      // [16]
    const float* __restrict__ rn,      // [16]
    const float* __restrict__ an0,     // [1]
    const float* __restrict__ an1,     // [1]
    float* __restrict__ out)           // [B,M,64]
{
    const int lane = threadIdx.x;             // one wave per block
    const int anchor = blockIdx.x;            // 0..4095
    const int b = anchor >> 11;
    const int col = lane & 15;
    const int grp = lane >> 4;

    // [k][src] and [comp][src], f16, row stride 136 (272B: <=4-way banks)
    __shared__ unsigned short eT[16][136];
    __shared__ unsigned short wT[4][136];

    const float NL2E = -1.44269504088896340736f;

    const float Rx = outc[(size_t)anchor * 3 + 0];
    const float Ry = outc[(size_t)anchor * 3 + 1];
    const float Rz = outc[(size_t)anchor * 3 + 2];

    f32x4 acc = {0.f, 0.f, 0.f, 0.f};

    const float* cb = coords + (size_t)b * NSRC * 3;
    const float* fb = f + (size_t)b * NSRC;

    // per-lane fragment base pointers (constant across iterations)
    const unsigned short* ea = &eT[col][4 * grp];
    const unsigned short* wb = &wT[col & 3][4 * grp];

    for (int i = 0; i < NSRC / 128; ++i) {    // 16 iterations, 128 src each
        const int sA = i * 128 + 2 * lane;    // lane handles (sA, sA+1)
        const float2 c0 = *(const float2*)(cb + (size_t)sA * 3);      // xA yA
        const float2 c1 = *(const float2*)(cb + (size_t)sA * 3 + 2);  // zA xB
        const float2 c2 = *(const float2*)(cb + (size_t)sA * 3 + 4);  // yB zB
        const float2 ff = *(const float2*)(fb + sA);                  // fA fB

        const float dxA = c0.x - Rx, dyA = c0.y - Ry, dzA = c1.x - Rz;
        const float dxB = c1.y - Rx, dyB = c2.x - Ry, dzB = c2.y - Rz;
        const float fvA = ff.x, fvB = ff.y;
        const float sqA = dxA * dxA + dyA * dyA + dzA * dzA;
        const float sqB = dxB * dxB + dyB * dyB + dzB * dzB;
        const float riA = __builtin_amdgcn_rsqf(sqA);
        const float riB = __builtin_amdgcn_rsqf(sqB);
        const float ddA = (sqA * riA) * NL2E;   // -log2e * |r-R|
        const float ddB = (sqB * riB) * NL2E;
        const float tA  = fvA * riA, tB = fvB * riB;
        const float fxA = tA * dxA, fyA = tA * dyA, fzA = tA * dzA;
        const float fxB = tB * dxB, fyB = tB * dyB, fzB = tB * dzB;

        // sqrt-chain in packed f16: ep[s] = E_{j=16-s} for (sA, sA+1)
        h2 ep[16];
#pragma unroll
        for (int s = 0; s < 8; ++s) {
            const float m_k = mu[15 - s];
            ep[s] = __builtin_amdgcn_cvt_pkrtz(
                __builtin_amdgcn_exp2f(ddA * m_k),
                __builtin_amdgcn_exp2f(ddB * m_k));
        }
        ep[8]  = ep[0] * ep[0];    // E8  = E16^2
        ep[9]  = ep[2] * ep[2];    // E7  = E14^2
        ep[10] = ep[4] * ep[4];    // E6  = E12^2
        ep[11] = ep[6] * ep[6];    // E5  = E10^2
        ep[12] = ep[8] * ep[8];    // E4  = E8^2
        ep[13] = ep[10] * ep[10];  // E3  = E6^2
        ep[14] = ep[12] * ep[12];  // E2  = E4^2
        ep[15] = ep[14] * ep[14];  // E1  = E2^2

        // scatter to LDS in transposed (fragment) layout
#pragma unroll
        for (int s = 0; s < 16; ++s)
            *(unsigned*)&eT[15 - s][2 * lane] = __builtin_bit_cast(unsigned, ep[s]);
        *(unsigned*)&wT[0][2 * lane] =
            __builtin_bit_cast(unsigned, __builtin_amdgcn_cvt_pkrtz(fvA, fvB));
        *(unsigned*)&wT[1][2 * lane] =
            __builtin_bit_cast(unsigned, __builtin_amdgcn_cvt_pkrtz(fxA, fxB));
        *(unsigned*)&wT[2][2 * lane] =
            __builtin_bit_cast(unsigned, __builtin_amdgcn_cvt_pkrtz(fyA, fyB));
        *(unsigned*)&wT[3][2 * lane] =
            __builtin_bit_cast(unsigned, __builtin_amdgcn_cvt_pkrtz(fzA, fzB));
        // single-wave block: DS ops are wave-ordered; compiler inserts lgkmcnt.

        // 4 MFMA chunks of 32 sources
#pragma unroll
        for (int c = 0; c < 4; ++c) {
            union { uint2 u2[2]; f16x8 v; } av, bv;
            av.u2[0] = *(const uint2*)(ea + 32 * c);        // K = 4g+e
            av.u2[1] = *(const uint2*)(ea + 32 * c + 16);   // K = 16+4g+e
            bv.u2[0] = *(const uint2*)(wb + 32 * c);
            bv.u2[1] = *(const uint2*)(wb + 32 * c + 16);
            acc = __builtin_amdgcn_mfma_f32_16x16x32_f16(av.v, bv.v, acc, 0, 0, 0);
        }
    }

    // D[row=4*grp+r][col] ; col = component (0..3 real), row = k.
    if (col < 4) {
        const float4 r4 = *(const float4*)&rn[4 * grp];
        const float an = (col == 0) ? an0[0] : an1[0];
        float4 o;
        o.x = acc[0] * r4.x * an;
        o.y = acc[1] * r4.y * an;
        o.z = acc[2] * r4.z * an;
        o.w = acc[3] * r4.w * an;
        *(float4*)&out[(size_t)anchor * 64 + col * 16 + 4 * grp] = o;
    }
}

extern "C" void kernel_launch(void* const* d_in, const int* in_sizes, int n_in,
                              void* d_out, int out_size, void* d_ws, size_t ws_size,
                              hipStream_t stream) {
    const float* f      = (const float*)d_in[0];
    const float* coords = (const float*)d_in[1];
    const float* outc   = (const float*)d_in[2];
    const float* mu     = (const float*)d_in[3];
    const float* rn     = (const float*)d_in[4];
    const float* an0    = (const float*)d_in[5];
    const float* an1    = (const float*)d_in[6];
    float* out = (float*)d_out;

    const int anchors = BATCH * MOUT;              // 4096 waves, 1 per block
    svp_kernel<<<anchors, 64, 0, stream>>>(f, coords, outc, mu, rn, an0, an1, out);
}